// Round 1
// baseline (616.087 us; speedup 1.0000x reference)
//
#include <hip/hip_runtime.h>

// ---- sizes ----
// x: (1024,1,28,28); h1: (1024,32,14,14); h2: (1024,64,14,14)->12544; out: (1024,10)
#define NB 1024
#define TOTAL1 (NB*196)

// ws layout (float offsets)
#define WS_H1   0               // 1024*32*196      = 6422528
#define WS_H2   6422528         // 1024*12544      = 12845056
#define WS_PART 19267584        // 32*1024*128     = 4194304
#define WS_W1T  23461888        // 288
#define WS_OW1T 23462176        // 162
#define WS_W2T  23462338        // 18432
#define WS_OW2T 23480770        // 5184
// end: 23485954 floats = 93.9 MB

// ---------------- weight transpose prep ----------------
__global__ __launch_bounds__(256) void prep(const float* __restrict__ w1,
                                            const float* __restrict__ ow1,
                                            const float* __restrict__ w2,
                                            const float* __restrict__ ow2,
                                            float* __restrict__ ws) {
  int i = blockIdx.x * 256 + threadIdx.x;
  if (i < 288)   { int co = i / 9,  kk = i % 9;   ws[WS_W1T  + kk * 32 + co] = w1[i]; }
  if (i < 162)   { int c  = i / 9,  j  = i % 9;   ws[WS_OW1T + j  * 18 + c ] = ow1[i]; }
  if (i < 18432) { int co = i / 288, k = i % 288; ws[WS_W2T  + k  * 64 + co] = w2[i]; }
  if (i < 5184)  { int c  = i / 288, k = i % 288; ws[WS_OW2T + k  * 18 + c ] = ow2[i]; }
}

// ---------------- stage 1: offset conv + deform conv (1->32) + relu + pool 28->14 ----------------
__global__ __launch_bounds__(256, 2) void stage1(const float* __restrict__ x,
                                                 const float* __restrict__ ob1,
                                                 const float* __restrict__ b1,
                                                 const float* __restrict__ ws,
                                                 float* __restrict__ h1) {
  __shared__ float ximg[3 * 784];
  const float* __restrict__ w1t  = ws + WS_W1T;   // [kk][32]
  const float* __restrict__ ow1t = ws + WS_OW1T;  // [j][18]
  int tid = threadIdx.x;
  int g0 = blockIdx.x * 256;
  int bfirst = g0 / 196;
  for (int idx = tid; idx < 3 * 784; idx += 256) {
    int img = idx / 784;
    int b = bfirst + img;
    ximg[idx] = (b < NB) ? x[b * 784 + (idx - img * 784)] : 0.f;
  }
  __syncthreads();
  int g = g0 + tid;
  if (g >= TOTAL1) return;
  int b = g / 196, p = g - b * 196;
  const float* im = ximg + (b - bfirst) * 784;
  int oy = p / 14, ox = p - (p / 14) * 14;

  float pooled[32];
#pragma unroll
  for (int co = 0; co < 32; ++co) pooled[co] = 0.f;

  for (int sub = 0; sub < 4; ++sub) {
    int y  = 2 * oy + (sub >> 1);
    int ix = 2 * ox + (sub & 1);
    // 3x3 input patch (zero pad)
    float patch[9];
#pragma unroll
    for (int j = 0; j < 9; ++j) {
      int yy = y + j / 3 - 1, xc = ix + j % 3 - 1;
      bool ok = (yy >= 0) & (yy < 28) & (xc >= 0) & (xc < 28);
      patch[j] = ok ? im[yy * 28 + xc] : 0.f;
    }
    // offset conv: 18 channels
    float off[18];
#pragma unroll
    for (int c = 0; c < 18; ++c) off[c] = ob1[c];
#pragma unroll
    for (int j = 0; j < 9; ++j) {
      float v = patch[j];
#pragma unroll
      for (int c = 0; c < 18; ++c) off[c] = fmaf(v, ow1t[j * 18 + c], off[c]);
    }
    // deformable sampling + conv (Cin=1)
    float a[32];
#pragma unroll
    for (int co = 0; co < 32; ++co) a[co] = b1[co];
#pragma unroll
    for (int kk = 0; kk < 9; ++kk) {
      float py = (float)(y - 1 + kk / 3) + off[2 * kk];
      float px = (float)(ix - 1 + kk % 3) + off[2 * kk + 1];
      float y0f = floorf(py), x0f = floorf(px);
      float wy1 = py - y0f, wx1 = px - x0f;
      float wy0 = 1.f - wy1, wx0 = 1.f - wx1;
      int y0 = (int)y0f, x0 = (int)x0f;
      int y1 = y0 + 1, x1 = x0 + 1;
      bool vy0 = (y0 >= 0) & (y0 < 28), vy1 = (y1 >= 0) & (y1 < 28);
      bool vx0 = (x0 >= 0) & (x0 < 28), vx1 = (x1 >= 0) & (x1 < 28);
      float W00 = (vy0 & vx0) ? wy0 * wx0 : 0.f;
      float W01 = (vy0 & vx1) ? wy0 * wx1 : 0.f;
      float W10 = (vy1 & vx0) ? wy1 * wx0 : 0.f;
      float W11 = (vy1 & vx1) ? wy1 * wx1 : 0.f;
      int yc0 = min(max(y0, 0), 27), yc1 = min(max(y1, 0), 27);
      int xc0 = min(max(x0, 0), 27), xc1 = min(max(x1, 0), 27);
      float s = im[yc0 * 28 + xc0] * W00 + im[yc0 * 28 + xc1] * W01 +
                im[yc1 * 28 + xc0] * W10 + im[yc1 * 28 + xc1] * W11;
#pragma unroll
      for (int co = 0; co < 32; ++co) a[co] = fmaf(s, w1t[kk * 32 + co], a[co]);
    }
#pragma unroll
    for (int co = 0; co < 32; ++co) pooled[co] += fmaxf(a[co], 0.f);
  }
#pragma unroll
  for (int co = 0; co < 32; ++co) h1[b * 6272 + co * 196 + p] = pooled[co] * 0.25f;
}

// ---------------- stage 2: offset conv (32->18) + deform conv (32->64) + relu ----------------
__global__ __launch_bounds__(256, 2) void stage2(const float* __restrict__ h1,
                                                 const float* __restrict__ ob2,
                                                 const float* __restrict__ b2,
                                                 const float* __restrict__ ws,
                                                 float* __restrict__ h2) {
  __shared__ float himg[3 * 6272];
  const float* __restrict__ w2t  = ws + WS_W2T;   // [ci*9+kk][64]
  const float* __restrict__ ow2t = ws + WS_OW2T;  // [ci*9+j][18]
  int tid = threadIdx.x;
  int g0 = blockIdx.x * 256;
  int bfirst = g0 / 196;
  for (int idx = tid; idx < 3 * 6272; idx += 256) {
    int img = idx / 6272;
    int b = bfirst + img;
    himg[idx] = (b < NB) ? h1[b * 6272 + (idx - img * 6272)] : 0.f;
  }
  __syncthreads();
  int g = g0 + tid;
  if (g >= TOTAL1) return;
  int b = g / 196, p = g - b * 196;
  const float* im = himg + (b - bfirst) * 6272;
  int y = p / 14, x = p - (p / 14) * 14;

  // patch index/validity shared across ci
  int  pidx[9];
  bool pok[9];
#pragma unroll
  for (int j = 0; j < 9; ++j) {
    int yy = y + j / 3 - 1, xc = x + j % 3 - 1;
    pok[j] = (yy >= 0) & (yy < 14) & (xc >= 0) & (xc < 14);
    pidx[j] = pok[j] ? (yy * 14 + xc) : 0;
  }
  // offset conv
  float off[18];
#pragma unroll
  for (int c = 0; c < 18; ++c) off[c] = ob2[c];
  for (int ci = 0; ci < 32; ++ci) {
    const float* imc = im + ci * 196;
    const float* wr  = ow2t + ci * 9 * 18;
#pragma unroll
    for (int j = 0; j < 9; ++j) {
      float v = pok[j] ? imc[pidx[j]] : 0.f;
#pragma unroll
      for (int c = 0; c < 18; ++c) off[c] = fmaf(v, wr[j * 18 + c], off[c]);
    }
  }
  // deformable conv
  float acc[64];
#pragma unroll
  for (int co = 0; co < 64; ++co) acc[co] = b2[co];
#pragma unroll
  for (int kk = 0; kk < 9; ++kk) {
    float py = (float)(y - 1 + kk / 3) + off[2 * kk];
    float px = (float)(x - 1 + kk % 3) + off[2 * kk + 1];
    float y0f = floorf(py), x0f = floorf(px);
    float wy1 = py - y0f, wx1 = px - x0f;
    float wy0 = 1.f - wy1, wx0 = 1.f - wx1;
    int y0 = (int)y0f, x0 = (int)x0f;
    int y1 = y0 + 1, x1 = x0 + 1;
    bool vy0 = (y0 >= 0) & (y0 < 14), vy1 = (y1 >= 0) & (y1 < 14);
    bool vx0 = (x0 >= 0) & (x0 < 14), vx1 = (x1 >= 0) & (x1 < 14);
    float W00 = (vy0 & vx0) ? wy0 * wx0 : 0.f;
    float W01 = (vy0 & vx1) ? wy0 * wx1 : 0.f;
    float W10 = (vy1 & vx0) ? wy1 * wx0 : 0.f;
    float W11 = (vy1 & vx1) ? wy1 * wx1 : 0.f;
    int yc0 = min(max(y0, 0), 13), yc1 = min(max(y1, 0), 13);
    int xc0 = min(max(x0, 0), 13), xc1 = min(max(x1, 0), 13);
    int i00 = yc0 * 14 + xc0, i01 = yc0 * 14 + xc1;
    int i10 = yc1 * 14 + xc0, i11 = yc1 * 14 + xc1;
    for (int ci = 0; ci < 32; ++ci) {
      const float* imc = im + ci * 196;
      float s = imc[i00] * W00 + imc[i01] * W01 + imc[i10] * W10 + imc[i11] * W11;
      const float* wr = w2t + (ci * 9 + kk) * 64;
#pragma unroll
      for (int co = 0; co < 64; ++co) acc[co] = fmaf(s, wr[co], acc[co]);
    }
  }
#pragma unroll
  for (int co = 0; co < 64; ++co)
    h2[b * 12544 + co * 196 + p] = fmaxf(acc[co], 0.f);
}

// ---------------- fc1: K-split GEMM 1024x128, K=12544 -> partials[32][1024][128] ----------------
__global__ __launch_bounds__(256, 2) void fc1(const float* __restrict__ h2,
                                              const float* __restrict__ fw1,
                                              float* __restrict__ part) {
  __shared__ float a_s[56 * 72];   // [k][r], stride 72 (16B-aligned rows)
  __shared__ float b_s[56 * 132];  // [k][c], stride 132
  int tid = threadIdx.x;
  int rb = (blockIdx.x & 15) * 64;
  int ks = blockIdx.x >> 4;
  int kbase = ks * 392;
  int c0 = (tid & 31) * 4;
  int r0 = (tid >> 5) * 8;

  float acc[8][4];
#pragma unroll
  for (int i = 0; i < 8; ++i)
#pragma unroll
    for (int j = 0; j < 4; ++j) acc[i][j] = 0.f;

  for (int ch = 0; ch < 7; ++ch) {
    int kb = kbase + ch * 56;
    __syncthreads();
#pragma unroll
    for (int t = 0; t < 14; ++t) {
      int idx = t * 256 + tid;
      int r = idx / 56, k = idx - r * 56;
      a_s[k * 72 + r] = h2[(rb + r) * 12544 + kb + k];
    }
#pragma unroll
    for (int t = 0; t < 28; ++t) {
      int idx = t * 256 + tid;
      int c = idx / 56, k = idx - c * 56;
      b_s[k * 132 + c] = fw1[c * 12544 + kb + k];
    }
    __syncthreads();
    for (int k = 0; k < 56; ++k) {
      float4 bv = *(const float4*)&b_s[k * 132 + c0];
      float4 av0 = *(const float4*)&a_s[k * 72 + r0];
      float4 av1 = *(const float4*)&a_s[k * 72 + r0 + 4];
      float av[8] = {av0.x, av0.y, av0.z, av0.w, av1.x, av1.y, av1.z, av1.w};
      float bj[4] = {bv.x, bv.y, bv.z, bv.w};
#pragma unroll
      for (int i = 0; i < 8; ++i)
#pragma unroll
        for (int j = 0; j < 4; ++j) acc[i][j] = fmaf(av[i], bj[j], acc[i][j]);
    }
  }
#pragma unroll
  for (int i = 0; i < 8; ++i) {
    int r = rb + r0 + i;
#pragma unroll
    for (int j = 0; j < 4; ++j)
      part[(ks * 1024 + r) * 128 + c0 + j] = acc[i][j];
  }
}

// ---------------- reduce partials + bias + relu + fc2 ----------------
__global__ __launch_bounds__(128) void fcfinal(const float* __restrict__ part,
                                               const float* __restrict__ fb1,
                                               const float* __restrict__ fw2,
                                               const float* __restrict__ fb2,
                                               float* __restrict__ out) {
  __shared__ float tbuf[128];
  int b = blockIdx.x, c = threadIdx.x;
  float s = fb1[c];
  for (int ks = 0; ks < 32; ++ks) s += part[(ks * 1024 + b) * 128 + c];
  tbuf[c] = fmaxf(s, 0.f);
  __syncthreads();
  if (c < 10) {
    float v = fb2[c];
#pragma unroll
    for (int k = 0; k < 128; ++k) v = fmaf(tbuf[k], fw2[c * 128 + k], v);
    out[b * 10 + c] = v;
  }
}

extern "C" void kernel_launch(void* const* d_in, const int* in_sizes, int n_in,
                              void* d_out, int out_size, void* d_ws, size_t ws_size,
                              hipStream_t stream) {
  const float* x   = (const float*)d_in[0];
  const float* ow1 = (const float*)d_in[1];
  const float* ob1 = (const float*)d_in[2];
  const float* w1  = (const float*)d_in[3];
  const float* b1  = (const float*)d_in[4];
  const float* ow2 = (const float*)d_in[5];
  const float* ob2 = (const float*)d_in[6];
  const float* w2  = (const float*)d_in[7];
  const float* b2  = (const float*)d_in[8];
  const float* fw1 = (const float*)d_in[9];
  const float* fb1 = (const float*)d_in[10];
  const float* fw2 = (const float*)d_in[11];
  const float* fb2 = (const float*)d_in[12];
  float* ws  = (float*)d_ws;
  float* out = (float*)d_out;

  prep<<<72, 256, 0, stream>>>(w1, ow1, w2, ow2, ws);
  stage1<<<784, 256, 0, stream>>>(x, ob1, b1, ws, ws + WS_H1);
  stage2<<<784, 256, 0, stream>>>(ws + WS_H1, ob2, b2, ws, ws + WS_H2);
  fc1<<<512, 256, 0, stream>>>(ws + WS_H2, fw1, ws + WS_PART);
  fcfinal<<<1024, 128, 0, stream>>>(ws + WS_PART, fb1, fw2, fb2, out);
}

// Round 2
// 424.525 us; speedup vs baseline: 1.4512x; 1.4512x over previous
//
#include <hip/hip_runtime.h>

// ---- sizes ----
// x: (1024,1,28,28); h1: (1024,32,14,14); h2: (1024,64,14,14)->12544; out: (1024,10)
#define NB 1024
#define TOTAL1 (NB*196)
#define SP 208   // padded pixel stride (13 float4 groups of 16B; 196 real + 12 pad)

// ws layout (float offsets)
#define WS_H1   0               // 1024*32*196      = 6422528
#define WS_H2   6422528         // 1024*12544      = 12845056
#define WS_PART 19267584        // 32*1024*128     = 4194304
#define WS_W1T  23461888        // 288
#define WS_OW1T 23462176        // 162
#define WS_W2T  23462338        // 18432  [k=ci*9+kk][co=64]
#define WS_OW2T 23480770        // 5184   [k=ci*9+j][c=18]
// end: 23485954 floats = 93.9 MB

// ---------------- weight transpose prep ----------------
__global__ __launch_bounds__(256) void prep(const float* __restrict__ w1,
                                            const float* __restrict__ ow1,
                                            const float* __restrict__ w2,
                                            const float* __restrict__ ow2,
                                            float* __restrict__ ws) {
  int i = blockIdx.x * 256 + threadIdx.x;
  if (i < 288)   { int co = i / 9,  kk = i % 9;   ws[WS_W1T  + kk * 32 + co] = w1[i]; }
  if (i < 162)   { int c  = i / 9,  j  = i % 9;   ws[WS_OW1T + j  * 18 + c ] = ow1[i]; }
  if (i < 18432) { int co = i / 288, k = i % 288; ws[WS_W2T  + k  * 64 + co] = w2[i]; }
  if (i < 5184)  { int c  = i / 288, k = i % 288; ws[WS_OW2T + k  * 18 + c ] = ow2[i]; }
}

// ---------------- stage 1: offset conv + deform conv (1->32) + relu + pool 28->14 ----------------
__global__ __launch_bounds__(256, 2) void stage1(const float* __restrict__ x,
                                                 const float* __restrict__ ob1,
                                                 const float* __restrict__ b1,
                                                 const float* __restrict__ ws,
                                                 float* __restrict__ h1) {
  __shared__ float ximg[3 * 784];
  const float* __restrict__ w1t  = ws + WS_W1T;   // [kk][32]
  const float* __restrict__ ow1t = ws + WS_OW1T;  // [j][18]
  int tid = threadIdx.x;
  int g0 = blockIdx.x * 256;
  int bfirst = g0 / 196;
  for (int idx = tid; idx < 3 * 784; idx += 256) {
    int img = idx / 784;
    int b = bfirst + img;
    ximg[idx] = (b < NB) ? x[b * 784 + (idx - img * 784)] : 0.f;
  }
  __syncthreads();
  int g = g0 + tid;
  if (g >= TOTAL1) return;
  int b = g / 196, p = g - b * 196;
  const float* im = ximg + (b - bfirst) * 784;
  int oy = p / 14, ox = p - (p / 14) * 14;

  float pooled[32];
#pragma unroll
  for (int co = 0; co < 32; ++co) pooled[co] = 0.f;

  for (int sub = 0; sub < 4; ++sub) {
    int y  = 2 * oy + (sub >> 1);
    int ix = 2 * ox + (sub & 1);
    float patch[9];
#pragma unroll
    for (int j = 0; j < 9; ++j) {
      int yy = y + j / 3 - 1, xc = ix + j % 3 - 1;
      bool ok = (yy >= 0) & (yy < 28) & (xc >= 0) & (xc < 28);
      patch[j] = ok ? im[yy * 28 + xc] : 0.f;
    }
    float off[18];
#pragma unroll
    for (int c = 0; c < 18; ++c) off[c] = ob1[c];
#pragma unroll
    for (int j = 0; j < 9; ++j) {
      float v = patch[j];
#pragma unroll
      for (int c = 0; c < 18; ++c) off[c] = fmaf(v, ow1t[j * 18 + c], off[c]);
    }
    float a[32];
#pragma unroll
    for (int co = 0; co < 32; ++co) a[co] = b1[co];
#pragma unroll
    for (int kk = 0; kk < 9; ++kk) {
      float py = (float)(y - 1 + kk / 3) + off[2 * kk];
      float px = (float)(ix - 1 + kk % 3) + off[2 * kk + 1];
      float y0f = floorf(py), x0f = floorf(px);
      float wy1 = py - y0f, wx1 = px - x0f;
      float wy0 = 1.f - wy1, wx0 = 1.f - wx1;
      int y0 = (int)y0f, x0 = (int)x0f;
      int y1 = y0 + 1, x1 = x0 + 1;
      bool vy0 = (y0 >= 0) & (y0 < 28), vy1 = (y1 >= 0) & (y1 < 28);
      bool vx0 = (x0 >= 0) & (x0 < 28), vx1 = (x1 >= 0) & (x1 < 28);
      float W00 = (vy0 & vx0) ? wy0 * wx0 : 0.f;
      float W01 = (vy0 & vx1) ? wy0 * wx1 : 0.f;
      float W10 = (vy1 & vx0) ? wy1 * wx0 : 0.f;
      float W11 = (vy1 & vx1) ? wy1 * wx1 : 0.f;
      int yc0 = min(max(y0, 0), 27), yc1 = min(max(y1, 0), 27);
      int xc0 = min(max(x0, 0), 27), xc1 = min(max(x1, 0), 27);
      float s = im[yc0 * 28 + xc0] * W00 + im[yc0 * 28 + xc1] * W01 +
                im[yc1 * 28 + xc0] * W10 + im[yc1 * 28 + xc1] * W11;
#pragma unroll
      for (int co = 0; co < 32; ++co) a[co] = fmaf(s, w1t[kk * 32 + co], a[co]);
    }
#pragma unroll
    for (int co = 0; co < 32; ++co) pooled[co] += fmaxf(a[co], 0.f);
  }
#pragma unroll
  for (int co = 0; co < 32; ++co) h1[b * 6272 + co * 196 + p] = pooled[co] * 0.25f;
}

// ---------------- stage 2 v2: per-image broadcast-GEMM deformable conv (32->64) ----------------
// Block = 1 image, 256 threads. LDS: imgT (transposed+rotated) + offs + S chunk.
// All hot-loop weight reads are per-lane VMEM (vmcnt); all S reads are wave-broadcast LDS.
__global__ __launch_bounds__(256, 2) void stage2(const float* __restrict__ h1,
                                                 const float* __restrict__ ob2,
                                                 const float* __restrict__ b2,
                                                 const float* __restrict__ ws,
                                                 float* __restrict__ h2) {
  __shared__ float imgT[196 * 32];   // imgT[p*32 + ((ci+4p)&31)] = img[ci][p]
  __shared__ float offs[18 * SP];    // offs[c*SP + p]
  __shared__ float Sbuf[32 * SP];    // S[ci*SP + p] (also used as P-chunk and store-transpose)
  const float* __restrict__ w2t  = ws + WS_W2T;
  const float* __restrict__ ow2t = ws + WS_OW2T;
  int tid = threadIdx.x;
  int b = blockIdx.x;

  // ---- phase 1: load image, transposed + bank-rotated ----
  for (int e = tid; e < 6272; e += 256) {
    int ci = e / 196, p = e - ci * 196;
    imgT[p * 32 + ((ci + 4 * p) & 31)] = h1[b * 6272 + e];
  }

  // sampler-thread identity (tid < SP builds P/S chunks)
  int pp = tid;
  int spy = pp / 14, spx = pp - (pp / 14) * 14;  // valid only for pp<196

  // offset-GEMM identity: 18 channels x 13 pixel-groups of 16 = 234 threads
  int oc  = tid % 18;
  int opg = tid / 18;          // 0..13 (13 used)
  int op0 = opg * 16;
  bool oact = (tid < 234);
  float oacc[16];
#pragma unroll
  for (int i = 0; i < 16; ++i) oacc[i] = 0.f;

  // ---- phase 2: offset conv as 9 broadcast-GEMM taps ----
  for (int j = 0; j < 9; ++j) {
    __syncthreads();  // Sbuf reuse guard (also covers phase-1 imgT writes on j==0)
    if (pp < SP) {
      if (pp < 196) {
        int yy = spy + j / 3 - 1, xx = spx + j % 3 - 1;
        bool ok = (yy >= 0) & (yy < 14) & (xx >= 0) & (xx < 14);
        int idx = ok ? (yy * 14 + xx) : 0;
        const float* src = imgT + idx * 32;
        int rot = (4 * idx) & 31;
#pragma unroll
        for (int cg = 0; cg < 8; ++cg) {
          float4 v;
          if (ok) v = *(const float4*)(src + ((cg * 4 + rot) & 31));
          else    v = make_float4(0.f, 0.f, 0.f, 0.f);
          Sbuf[(cg * 4 + 0) * SP + pp] = v.x;
          Sbuf[(cg * 4 + 1) * SP + pp] = v.y;
          Sbuf[(cg * 4 + 2) * SP + pp] = v.z;
          Sbuf[(cg * 4 + 3) * SP + pp] = v.w;
        }
      } else {
#pragma unroll
        for (int ci2 = 0; ci2 < 32; ++ci2) Sbuf[ci2 * SP + pp] = 0.f;
      }
    }
    __syncthreads();
    if (oact) {
      float wv[32];
#pragma unroll
      for (int ci2 = 0; ci2 < 32; ++ci2) wv[ci2] = ow2t[(ci2 * 9 + j) * 18 + oc];
      for (int ci2 = 0; ci2 < 32; ++ci2) {
        const float* srow = Sbuf + ci2 * SP + op0;
        float w = wv[ci2];
#pragma unroll
        for (int t = 0; t < 4; ++t) {
          float4 s = *(const float4*)(srow + 4 * t);
          oacc[4 * t + 0] = fmaf(w, s.x, oacc[4 * t + 0]);
          oacc[4 * t + 1] = fmaf(w, s.y, oacc[4 * t + 1]);
          oacc[4 * t + 2] = fmaf(w, s.z, oacc[4 * t + 2]);
          oacc[4 * t + 3] = fmaf(w, s.w, oacc[4 * t + 3]);
        }
      }
    }
  }
  __syncthreads();
  // ---- phase 3: write offsets (+bias) ----
  if (oact) {
    float bo = ob2[oc];
#pragma unroll
    for (int i = 0; i < 16; ++i) offs[oc * SP + op0 + i] = oacc[i] + bo;
  }

  // ---- phase 4: 9 taps of sample -> broadcast GEMM ----
  int co = tid & 63, pg = tid >> 6;
  int p0 = pg * 52;
  float bb = b2[co];
  float acc[52];
#pragma unroll
  for (int i = 0; i < 52; ++i) acc[i] = bb;

  for (int kk = 0; kk < 9; ++kk) {
    __syncthreads();  // offs ready (kk==0) / previous GEMM done reading Sbuf
    if (pp < SP) {
      if (pp < 196) {
        float dyv = offs[(2 * kk) * SP + pp];
        float dxv = offs[(2 * kk + 1) * SP + pp];
        float pyv = (float)(spy - 1 + kk / 3) + dyv;
        float pxv = (float)(spx - 1 + kk % 3) + dxv;
        float y0f = floorf(pyv), x0f = floorf(pxv);
        float wy1 = pyv - y0f, wx1 = pxv - x0f;
        float wy0 = 1.f - wy1, wx0 = 1.f - wx1;
        int y0 = (int)y0f, x0 = (int)x0f;
        int y1 = y0 + 1, x1 = x0 + 1;
        bool vy0 = (y0 >= 0) & (y0 < 14), vy1 = (y1 >= 0) & (y1 < 14);
        bool vx0 = (x0 >= 0) & (x0 < 14), vx1 = (x1 >= 0) & (x1 < 14);
        float W00 = (vy0 & vx0) ? wy0 * wx0 : 0.f;
        float W01 = (vy0 & vx1) ? wy0 * wx1 : 0.f;
        float W10 = (vy1 & vx0) ? wy1 * wx0 : 0.f;
        float W11 = (vy1 & vx1) ? wy1 * wx1 : 0.f;
        int yc0 = min(max(y0, 0), 13), yc1 = min(max(y1, 0), 13);
        int xc0 = min(max(x0, 0), 13), xc1 = min(max(x1, 0), 13);
        int i00 = yc0 * 14 + xc0, i01 = yc0 * 14 + xc1;
        int i10 = yc1 * 14 + xc0, i11 = yc1 * 14 + xc1;
        const float* s00 = imgT + i00 * 32; int r00 = (4 * i00) & 31;
        const float* s01 = imgT + i01 * 32; int r01 = (4 * i01) & 31;
        const float* s10 = imgT + i10 * 32; int r10 = (4 * i10) & 31;
        const float* s11 = imgT + i11 * 32; int r11 = (4 * i11) & 31;
#pragma unroll
        for (int cg = 0; cg < 8; ++cg) {
          float4 a0 = *(const float4*)(s00 + ((cg * 4 + r00) & 31));
          float4 a1 = *(const float4*)(s01 + ((cg * 4 + r01) & 31));
          float4 a2 = *(const float4*)(s10 + ((cg * 4 + r10) & 31));
          float4 a3 = *(const float4*)(s11 + ((cg * 4 + r11) & 31));
          float vx0v = fmaf(W00, a0.x, fmaf(W01, a1.x, fmaf(W10, a2.x, W11 * a3.x)));
          float vy0v = fmaf(W00, a0.y, fmaf(W01, a1.y, fmaf(W10, a2.y, W11 * a3.y)));
          float vz0v = fmaf(W00, a0.z, fmaf(W01, a1.z, fmaf(W10, a2.z, W11 * a3.z)));
          float vw0v = fmaf(W00, a0.w, fmaf(W01, a1.w, fmaf(W10, a2.w, W11 * a3.w)));
          Sbuf[(cg * 4 + 0) * SP + pp] = vx0v;
          Sbuf[(cg * 4 + 1) * SP + pp] = vy0v;
          Sbuf[(cg * 4 + 2) * SP + pp] = vz0v;
          Sbuf[(cg * 4 + 3) * SP + pp] = vw0v;
        }
      } else {
#pragma unroll
        for (int ci2 = 0; ci2 < 32; ++ci2) Sbuf[ci2 * SP + pp] = 0.f;
      }
    }
    __syncthreads();
    float wv[32];
#pragma unroll
    for (int ci2 = 0; ci2 < 32; ++ci2) wv[ci2] = w2t[(ci2 * 9 + kk) * 64 + co];
#pragma unroll 2
    for (int ci2 = 0; ci2 < 32; ++ci2) {
      const float* srow = Sbuf + ci2 * SP + p0;
      float w = wv[ci2];
#pragma unroll
      for (int t = 0; t < 13; ++t) {
        float4 s = *(const float4*)(srow + 4 * t);
        acc[4 * t + 0] = fmaf(w, s.x, acc[4 * t + 0]);
        acc[4 * t + 1] = fmaf(w, s.y, acc[4 * t + 1]);
        acc[4 * t + 2] = fmaf(w, s.z, acc[4 * t + 2]);
        acc[4 * t + 3] = fmaf(w, s.w, acc[4 * t + 3]);
      }
    }
  }

  // ---- phase 5: ReLU + coalesced store via LDS transpose (two co-halves) ----
  for (int half = 0; half < 2; ++half) {
    __syncthreads();
    if ((co >> 5) == half) {
      int cc = co & 31;
#pragma unroll
      for (int i = 0; i < 52; ++i) Sbuf[cc * SP + p0 + i] = acc[i];
    }
    __syncthreads();
    for (int e = tid; e < 6272; e += 256) {
      int cc = e / 196, p = e - cc * 196;
      h2[b * 12544 + (half * 32 + cc) * 196 + p] = fmaxf(Sbuf[cc * SP + p], 0.f);
    }
  }
}

// ---------------- fc1: K-split GEMM 1024x128, K=12544 -> partials[32][1024][128] ----------------
__global__ __launch_bounds__(256, 2) void fc1(const float* __restrict__ h2,
                                              const float* __restrict__ fw1,
                                              float* __restrict__ part) {
  __shared__ float a_s[56 * 72];   // [k][r]
  __shared__ float b_s[56 * 132];  // [k][c]
  int tid = threadIdx.x;
  int rb = (blockIdx.x & 15) * 64;
  int ks = blockIdx.x >> 4;
  int kbase = ks * 392;
  int c0 = (tid & 31) * 4;
  int r0 = (tid >> 5) * 8;

  float acc[8][4];
#pragma unroll
  for (int i = 0; i < 8; ++i)
#pragma unroll
    for (int j = 0; j < 4; ++j) acc[i][j] = 0.f;

  for (int ch = 0; ch < 7; ++ch) {
    int kb = kbase + ch * 56;
    __syncthreads();
#pragma unroll
    for (int t = 0; t < 14; ++t) {
      int idx = t * 256 + tid;
      int r = idx / 56, k = idx - r * 56;
      a_s[k * 72 + r] = h2[(rb + r) * 12544 + kb + k];
    }
#pragma unroll
    for (int t = 0; t < 28; ++t) {
      int idx = t * 256 + tid;
      int c = idx / 56, k = idx - c * 56;
      b_s[k * 132 + c] = fw1[c * 12544 + kb + k];
    }
    __syncthreads();
    for (int k = 0; k < 56; ++k) {
      float4 bv = *(const float4*)&b_s[k * 132 + c0];
      float4 av0 = *(const float4*)&a_s[k * 72 + r0];
      float4 av1 = *(const float4*)&a_s[k * 72 + r0 + 4];
      float av[8] = {av0.x, av0.y, av0.z, av0.w, av1.x, av1.y, av1.z, av1.w};
      float bj[4] = {bv.x, bv.y, bv.z, bv.w};
#pragma unroll
      for (int i = 0; i < 8; ++i)
#pragma unroll
        for (int j = 0; j < 4; ++j) acc[i][j] = fmaf(av[i], bj[j], acc[i][j]);
    }
  }
#pragma unroll
  for (int i = 0; i < 8; ++i) {
    int r = rb + r0 + i;
#pragma unroll
    for (int j = 0; j < 4; ++j)
      part[(ks * 1024 + r) * 128 + c0 + j] = acc[i][j];
  }
}

// ---------------- reduce partials + bias + relu + fc2 ----------------
__global__ __launch_bounds__(128) void fcfinal(const float* __restrict__ part,
                                               const float* __restrict__ fb1,
                                               const float* __restrict__ fw2,
                                               const float* __restrict__ fb2,
                                               float* __restrict__ out) {
  __shared__ float tbuf[128];
  int b = blockIdx.x, c = threadIdx.x;
  float s = fb1[c];
  for (int ks = 0; ks < 32; ++ks) s += part[(ks * 1024 + b) * 128 + c];
  tbuf[c] = fmaxf(s, 0.f);
  __syncthreads();
  if (c < 10) {
    float v = fb2[c];
#pragma unroll
    for (int k = 0; k < 128; ++k) v = fmaf(tbuf[k], fw2[c * 128 + k], v);
    out[b * 10 + c] = v;
  }
}

extern "C" void kernel_launch(void* const* d_in, const int* in_sizes, int n_in,
                              void* d_out, int out_size, void* d_ws, size_t ws_size,
                              hipStream_t stream) {
  const float* x   = (const float*)d_in[0];
  const float* ow1 = (const float*)d_in[1];
  const float* ob1 = (const float*)d_in[2];
  const float* w1  = (const float*)d_in[3];
  const float* b1  = (const float*)d_in[4];
  const float* ow2 = (const float*)d_in[5];
  const float* ob2 = (const float*)d_in[6];
  const float* w2  = (const float*)d_in[7];
  const float* b2  = (const float*)d_in[8];
  const float* fw1 = (const float*)d_in[9];
  const float* fb1 = (const float*)d_in[10];
  const float* fw2 = (const float*)d_in[11];
  const float* fb2 = (const float*)d_in[12];
  float* ws  = (float*)d_ws;
  float* out = (float*)d_out;

  prep<<<72, 256, 0, stream>>>(w1, ow1, w2, ow2, ws);
  stage1<<<784, 256, 0, stream>>>(x, ob1, b1, ws, ws + WS_H1);
  stage2<<<NB, 256, 0, stream>>>(ws + WS_H1, ob2, b2, ws, ws + WS_H2);
  fc1<<<512, 256, 0, stream>>>(ws + WS_H2, fw1, ws + WS_PART);
  fcfinal<<<1024, 128, 0, stream>>>(ws + WS_PART, fb1, fw2, fb2, out);
}

// Round 3
// 385.692 us; speedup vs baseline: 1.5974x; 1.1007x over previous
//
#include <hip/hip_runtime.h>

// ---- sizes ----
// x: (1024,1,28,28); h1: (1024,32,14,14); h2: (1024,64,14,14)->12544; out: (1024,10)
#define NB 1024
#define TOTAL1 (NB*196)
#define SP 208   // padded pixel stride (13 groups of 16)

// ws layout (float offsets)
#define WS_H1   0               // 1024*32*196      = 6422528
#define WS_H2   6422528         // 1024*12544      = 12845056
#define WS_PART 19267584        // 32*1024*128     = 4194304
#define WS_W1T  23461888        // 288
#define WS_OW1T 23462176        // 162
#define WS_W2T  23462338        // 18432  [k=ci*9+kk][co=64]
#define WS_OW2T 23480770        // 5184   [k=ci*9+j][c=18]
// end: 23485954 floats = 93.9 MB

// ---------------- weight transpose prep ----------------
__global__ __launch_bounds__(256) void prep(const float* __restrict__ w1,
                                            const float* __restrict__ ow1,
                                            const float* __restrict__ w2,
                                            const float* __restrict__ ow2,
                                            float* __restrict__ ws) {
  int i = blockIdx.x * 256 + threadIdx.x;
  if (i < 288)   { int co = i / 9,  kk = i % 9;   ws[WS_W1T  + kk * 32 + co] = w1[i]; }
  if (i < 162)   { int c  = i / 9,  j  = i % 9;   ws[WS_OW1T + j  * 18 + c ] = ow1[i]; }
  if (i < 18432) { int co = i / 288, k = i % 288; ws[WS_W2T  + k  * 64 + co] = w2[i]; }
  if (i < 5184)  { int c  = i / 288, k = i % 288; ws[WS_OW2T + k  * 18 + c ] = ow2[i]; }
}

// ---------------- stage 1: offset conv + deform conv (1->32) + relu + pool 28->14 ----------------
__global__ __launch_bounds__(256, 2) void stage1(const float* __restrict__ x,
                                                 const float* __restrict__ ob1,
                                                 const float* __restrict__ b1,
                                                 const float* __restrict__ ws,
                                                 float* __restrict__ h1) {
  __shared__ float ximg[3 * 784];
  const float* __restrict__ w1t  = ws + WS_W1T;   // [kk][32]
  const float* __restrict__ ow1t = ws + WS_OW1T;  // [j][18]
  int tid = threadIdx.x;
  int g0 = blockIdx.x * 256;
  int bfirst = g0 / 196;
  for (int idx = tid; idx < 3 * 784; idx += 256) {
    int img = idx / 784;
    int b = bfirst + img;
    ximg[idx] = (b < NB) ? x[b * 784 + (idx - img * 784)] : 0.f;
  }
  __syncthreads();
  int g = g0 + tid;
  if (g >= TOTAL1) return;
  int b = g / 196, p = g - b * 196;
  const float* im = ximg + (b - bfirst) * 784;
  int oy = p / 14, ox = p - (p / 14) * 14;

  float pooled[32];
#pragma unroll
  for (int co = 0; co < 32; ++co) pooled[co] = 0.f;

  for (int sub = 0; sub < 4; ++sub) {
    int y  = 2 * oy + (sub >> 1);
    int ix = 2 * ox + (sub & 1);
    float patch[9];
#pragma unroll
    for (int j = 0; j < 9; ++j) {
      int yy = y + j / 3 - 1, xc = ix + j % 3 - 1;
      bool ok = (yy >= 0) & (yy < 28) & (xc >= 0) & (xc < 28);
      patch[j] = ok ? im[yy * 28 + xc] : 0.f;
    }
    float off[18];
#pragma unroll
    for (int c = 0; c < 18; ++c) off[c] = ob1[c];
#pragma unroll
    for (int j = 0; j < 9; ++j) {
      float v = patch[j];
#pragma unroll
      for (int c = 0; c < 18; ++c) off[c] = fmaf(v, ow1t[j * 18 + c], off[c]);
    }
    float a[32];
#pragma unroll
    for (int co = 0; co < 32; ++co) a[co] = b1[co];
#pragma unroll
    for (int kk = 0; kk < 9; ++kk) {
      float py = (float)(y - 1 + kk / 3) + off[2 * kk];
      float px = (float)(ix - 1 + kk % 3) + off[2 * kk + 1];
      float y0f = floorf(py), x0f = floorf(px);
      float wy1 = py - y0f, wx1 = px - x0f;
      float wy0 = 1.f - wy1, wx0 = 1.f - wx1;
      int y0 = (int)y0f, x0 = (int)x0f;
      int y1 = y0 + 1, x1 = x0 + 1;
      bool vy0 = (y0 >= 0) & (y0 < 28), vy1 = (y1 >= 0) & (y1 < 28);
      bool vx0 = (x0 >= 0) & (x0 < 28), vx1 = (x1 >= 0) & (x1 < 28);
      float W00 = (vy0 & vx0) ? wy0 * wx0 : 0.f;
      float W01 = (vy0 & vx1) ? wy0 * wx1 : 0.f;
      float W10 = (vy1 & vx0) ? wy1 * wx0 : 0.f;
      float W11 = (vy1 & vx1) ? wy1 * wx1 : 0.f;
      int yc0 = min(max(y0, 0), 27), yc1 = min(max(y1, 0), 27);
      int xc0 = min(max(x0, 0), 27), xc1 = min(max(x1, 0), 27);
      float s = im[yc0 * 28 + xc0] * W00 + im[yc0 * 28 + xc1] * W01 +
                im[yc1 * 28 + xc0] * W10 + im[yc1 * 28 + xc1] * W11;
#pragma unroll
      for (int co = 0; co < 32; ++co) a[co] = fmaf(s, w1t[kk * 32 + co], a[co]);
    }
#pragma unroll
    for (int co = 0; co < 32; ++co) pooled[co] += fmaxf(a[co], 0.f);
  }
#pragma unroll
  for (int co = 0; co < 32; ++co) h1[b * 6272 + co * 196 + p] = pooled[co] * 0.25f;
}

// ---------------- stage 2 v3: per-image broadcast-GEMM, 4co x 16px register tiles ----------------
// Block = 1 image, 256 threads. GEMM thread = (pg=tid>>4 in [0,13), cog=tid&15):
// acc[4 co][16 px]; per ci: 4 ds_read_b128 (broadcast x16 lanes, 2-way bank alias = free)
// + 1 global float4 weight load (L2-resident) + 64 FMAs -> 16:1 FMA:LDS ratio.
__global__ __launch_bounds__(256, 2) void stage2(const float* __restrict__ h1,
                                                 const float* __restrict__ ob2,
                                                 const float* __restrict__ b2,
                                                 const float* __restrict__ ws,
                                                 float* __restrict__ h2) {
  __shared__ float imgT[196 * 32];   // imgT[p*32 + ((ci+4p)&31)] = img[ci][p]
  __shared__ float offs[18 * SP];    // offs[c*SP + p]
  __shared__ float Sbuf[32 * SP];    // S[ci*SP + p]
  const float* __restrict__ w2t  = ws + WS_W2T;
  const float* __restrict__ ow2t = ws + WS_OW2T;
  int tid = threadIdx.x;
  int b = blockIdx.x;

  // ---- phase 1: load image, transposed + bank-rotated ----
  for (int e = tid; e < 6272; e += 256) {
    int ci = e / 196, p = e - ci * 196;
    imgT[p * 32 + ((ci + 4 * p) & 31)] = h1[b * 6272 + e];
  }

  // sampler identity (tid < SP)
  int pp = tid;
  int spy = pp / 14, spx = pp - (pp / 14) * 14;

  // offset-GEMM identity: 18 channels x 13 pixel-groups of 16 = 234 threads
  int oc  = tid % 18;
  int opg = tid / 18;
  int op0 = opg * 16;
  bool oact = (tid < 234);
  float oacc[16];
#pragma unroll
  for (int i = 0; i < 16; ++i) oacc[i] = 0.f;

  // ---- phase 2: offset conv as 9 broadcast-GEMM taps ----
  for (int j = 0; j < 9; ++j) {
    __syncthreads();
    if (pp < SP) {
      if (pp < 196) {
        int yy = spy + j / 3 - 1, xx = spx + j % 3 - 1;
        bool ok = (yy >= 0) & (yy < 14) & (xx >= 0) & (xx < 14);
        int idx = ok ? (yy * 14 + xx) : 0;
        const float* src = imgT + idx * 32;
        int rot = (4 * idx) & 31;
#pragma unroll
        for (int cg = 0; cg < 8; ++cg) {
          float4 v;
          if (ok) v = *(const float4*)(src + ((cg * 4 + rot) & 31));
          else    v = make_float4(0.f, 0.f, 0.f, 0.f);
          Sbuf[(cg * 4 + 0) * SP + pp] = v.x;
          Sbuf[(cg * 4 + 1) * SP + pp] = v.y;
          Sbuf[(cg * 4 + 2) * SP + pp] = v.z;
          Sbuf[(cg * 4 + 3) * SP + pp] = v.w;
        }
      } else {
#pragma unroll
        for (int ci2 = 0; ci2 < 32; ++ci2) Sbuf[ci2 * SP + pp] = 0.f;
      }
    }
    __syncthreads();
    if (oact) {
      float wv[32];
#pragma unroll
      for (int ci2 = 0; ci2 < 32; ++ci2) wv[ci2] = ow2t[(ci2 * 9 + j) * 18 + oc];
      for (int ci2 = 0; ci2 < 32; ++ci2) {
        const float* srow = Sbuf + ci2 * SP + op0;
        float w = wv[ci2];
#pragma unroll
        for (int t = 0; t < 4; ++t) {
          float4 s = *(const float4*)(srow + 4 * t);
          oacc[4 * t + 0] = fmaf(w, s.x, oacc[4 * t + 0]);
          oacc[4 * t + 1] = fmaf(w, s.y, oacc[4 * t + 1]);
          oacc[4 * t + 2] = fmaf(w, s.z, oacc[4 * t + 2]);
          oacc[4 * t + 3] = fmaf(w, s.w, oacc[4 * t + 3]);
        }
      }
    }
  }
  __syncthreads();
  // ---- phase 3: write offsets (+bias) ----
  if (oact) {
    float bo = ob2[oc];
#pragma unroll
    for (int i = 0; i < 16; ++i) offs[oc * SP + op0 + i] = oacc[i] + bo;
  }

  // ---- phase 4: 9 taps of sample -> register-tiled broadcast GEMM ----
  int cog = tid & 15, pg = tid >> 4;
  int co0 = cog * 4;
  int p0 = pg * 16;
  bool gact = (pg < 13);
  float acc[4][16];
  {
    float4 bb = *(const float4*)(b2 + co0);
    float bj[4] = {bb.x, bb.y, bb.z, bb.w};
#pragma unroll
    for (int j = 0; j < 4; ++j)
#pragma unroll
      for (int i = 0; i < 16; ++i) acc[j][i] = bj[j];
  }

  for (int kk = 0; kk < 9; ++kk) {
    __syncthreads();  // offs ready (kk==0) / previous GEMM done reading Sbuf
    if (pp < SP) {
      if (pp < 196) {
        float dyv = offs[(2 * kk) * SP + pp];
        float dxv = offs[(2 * kk + 1) * SP + pp];
        float pyv = (float)(spy - 1 + kk / 3) + dyv;
        float pxv = (float)(spx - 1 + kk % 3) + dxv;
        float y0f = floorf(pyv), x0f = floorf(pxv);
        float wy1 = pyv - y0f, wx1 = pxv - x0f;
        float wy0 = 1.f - wy1, wx0 = 1.f - wx1;
        int y0 = (int)y0f, x0 = (int)x0f;
        int y1 = y0 + 1, x1 = x0 + 1;
        bool vy0 = (y0 >= 0) & (y0 < 14), vy1 = (y1 >= 0) & (y1 < 14);
        bool vx0 = (x0 >= 0) & (x0 < 14), vx1 = (x1 >= 0) & (x1 < 14);
        float W00 = (vy0 & vx0) ? wy0 * wx0 : 0.f;
        float W01 = (vy0 & vx1) ? wy0 * wx1 : 0.f;
        float W10 = (vy1 & vx0) ? wy1 * wx0 : 0.f;
        float W11 = (vy1 & vx1) ? wy1 * wx1 : 0.f;
        int yc0 = min(max(y0, 0), 13), yc1 = min(max(y1, 0), 13);
        int xc0 = min(max(x0, 0), 13), xc1 = min(max(x1, 0), 13);
        int i00 = yc0 * 14 + xc0, i01 = yc0 * 14 + xc1;
        int i10 = yc1 * 14 + xc0, i11 = yc1 * 14 + xc1;
        const float* s00 = imgT + i00 * 32; int r00 = (4 * i00) & 31;
        const float* s01 = imgT + i01 * 32; int r01 = (4 * i01) & 31;
        const float* s10 = imgT + i10 * 32; int r10 = (4 * i10) & 31;
        const float* s11 = imgT + i11 * 32; int r11 = (4 * i11) & 31;
#pragma unroll
        for (int cg = 0; cg < 8; ++cg) {
          float4 a0 = *(const float4*)(s00 + ((cg * 4 + r00) & 31));
          float4 a1 = *(const float4*)(s01 + ((cg * 4 + r01) & 31));
          float4 a2 = *(const float4*)(s10 + ((cg * 4 + r10) & 31));
          float4 a3 = *(const float4*)(s11 + ((cg * 4 + r11) & 31));
          Sbuf[(cg * 4 + 0) * SP + pp] = fmaf(W00, a0.x, fmaf(W01, a1.x, fmaf(W10, a2.x, W11 * a3.x)));
          Sbuf[(cg * 4 + 1) * SP + pp] = fmaf(W00, a0.y, fmaf(W01, a1.y, fmaf(W10, a2.y, W11 * a3.y)));
          Sbuf[(cg * 4 + 2) * SP + pp] = fmaf(W00, a0.z, fmaf(W01, a1.z, fmaf(W10, a2.z, W11 * a3.z)));
          Sbuf[(cg * 4 + 3) * SP + pp] = fmaf(W00, a0.w, fmaf(W01, a1.w, fmaf(W10, a2.w, W11 * a3.w)));
        }
      } else {
#pragma unroll
        for (int ci2 = 0; ci2 < 32; ++ci2) Sbuf[ci2 * SP + pp] = 0.f;
      }
    }
    __syncthreads();
    if (gact) {
      // 32 ci in chunks of 8: batch-preload 8 weight quads (VMEM, L2-hit), then FMA
      for (int cb = 0; cb < 32; cb += 8) {
        float4 w[8];
#pragma unroll
        for (int u = 0; u < 8; ++u)
          w[u] = *(const float4*)(w2t + ((cb + u) * 9 + kk) * 64 + co0);
#pragma unroll
        for (int u = 0; u < 8; ++u) {
          const float* srow = Sbuf + (cb + u) * SP + p0;
          float4 s0 = *(const float4*)(srow);
          float4 s1 = *(const float4*)(srow + 4);
          float4 s2 = *(const float4*)(srow + 8);
          float4 s3 = *(const float4*)(srow + 12);
          float sv[16] = {s0.x, s0.y, s0.z, s0.w, s1.x, s1.y, s1.z, s1.w,
                          s2.x, s2.y, s2.z, s2.w, s3.x, s3.y, s3.z, s3.w};
          float wj[4] = {w[u].x, w[u].y, w[u].z, w[u].w};
#pragma unroll
          for (int j = 0; j < 4; ++j)
#pragma unroll
            for (int i = 0; i < 16; ++i)
              acc[j][i] = fmaf(wj[j], sv[i], acc[j][i]);
        }
      }
    }
  }

  // ---- phase 5: ReLU + direct float4 global stores ----
  if (gact) {
    float* __restrict__ orow = h2 + b * 12544 + co0 * 196 + p0;
#pragma unroll
    for (int j = 0; j < 4; ++j) {
#pragma unroll
      for (int t = 0; t < 4; ++t) {
        if (p0 + 4 * t < 196) {
          float4 v;
          v.x = fmaxf(acc[j][4 * t + 0], 0.f);
          v.y = fmaxf(acc[j][4 * t + 1], 0.f);
          v.z = fmaxf(acc[j][4 * t + 2], 0.f);
          v.w = fmaxf(acc[j][4 * t + 3], 0.f);
          *(float4*)(orow + j * 196 + 4 * t) = v;
        }
      }
    }
  }
}

// ---------------- fc1: K-split GEMM 1024x128, K=12544 -> partials[32][1024][128] ----------------
__global__ __launch_bounds__(256, 2) void fc1(const float* __restrict__ h2,
                                              const float* __restrict__ fw1,
                                              float* __restrict__ part) {
  __shared__ float a_s[56 * 72];   // [k][r]
  __shared__ float b_s[56 * 132];  // [k][c]
  int tid = threadIdx.x;
  int rb = (blockIdx.x & 15) * 64;
  int ks = blockIdx.x >> 4;
  int kbase = ks * 392;
  int c0 = (tid & 31) * 4;
  int r0 = (tid >> 5) * 8;

  float acc[8][4];
#pragma unroll
  for (int i = 0; i < 8; ++i)
#pragma unroll
    for (int j = 0; j < 4; ++j) acc[i][j] = 0.f;

  for (int ch = 0; ch < 7; ++ch) {
    int kb = kbase + ch * 56;
    __syncthreads();
#pragma unroll
    for (int t = 0; t < 14; ++t) {
      int idx = t * 256 + tid;
      int r = idx / 56, k = idx - r * 56;
      a_s[k * 72 + r] = h2[(rb + r) * 12544 + kb + k];
    }
#pragma unroll
    for (int t = 0; t < 28; ++t) {
      int idx = t * 256 + tid;
      int c = idx / 56, k = idx - c * 56;
      b_s[k * 132 + c] = fw1[c * 12544 + kb + k];
    }
    __syncthreads();
    for (int k = 0; k < 56; ++k) {
      float4 bv = *(const float4*)&b_s[k * 132 + c0];
      float4 av0 = *(const float4*)&a_s[k * 72 + r0];
      float4 av1 = *(const float4*)&a_s[k * 72 + r0 + 4];
      float av[8] = {av0.x, av0.y, av0.z, av0.w, av1.x, av1.y, av1.z, av1.w};
      float bj[4] = {bv.x, bv.y, bv.z, bv.w};
#pragma unroll
      for (int i = 0; i < 8; ++i)
#pragma unroll
        for (int j = 0; j < 4; ++j) acc[i][j] = fmaf(av[i], bj[j], acc[i][j]);
    }
  }
#pragma unroll
  for (int i = 0; i < 8; ++i) {
    int r = rb + r0 + i;
#pragma unroll
    for (int j = 0; j < 4; ++j)
      part[(ks * 1024 + r) * 128 + c0 + j] = acc[i][j];
  }
}

// ---------------- reduce partials + bias + relu + fc2 ----------------
__global__ __launch_bounds__(128) void fcfinal(const float* __restrict__ part,
                                               const float* __restrict__ fb1,
                                               const float* __restrict__ fw2,
                                               const float* __restrict__ fb2,
                                               float* __restrict__ out) {
  __shared__ float tbuf[128];
  int b = blockIdx.x, c = threadIdx.x;
  float s = fb1[c];
  for (int ks = 0; ks < 32; ++ks) s += part[(ks * 1024 + b) * 128 + c];
  tbuf[c] = fmaxf(s, 0.f);
  __syncthreads();
  if (c < 10) {
    float v = fb2[c];
#pragma unroll
    for (int k = 0; k < 128; ++k) v = fmaf(tbuf[k], fw2[c * 128 + k], v);
    out[b * 10 + c] = v;
  }
}

extern "C" void kernel_launch(void* const* d_in, const int* in_sizes, int n_in,
                              void* d_out, int out_size, void* d_ws, size_t ws_size,
                              hipStream_t stream) {
  const float* x   = (const float*)d_in[0];
  const float* ow1 = (const float*)d_in[1];
  const float* ob1 = (const float*)d_in[2];
  const float* w1  = (const float*)d_in[3];
  const float* b1  = (const float*)d_in[4];
  const float* ow2 = (const float*)d_in[5];
  const float* ob2 = (const float*)d_in[6];
  const float* w2  = (const float*)d_in[7];
  const float* b2  = (const float*)d_in[8];
  const float* fw1 = (const float*)d_in[9];
  const float* fb1 = (const float*)d_in[10];
  const float* fw2 = (const float*)d_in[11];
  const float* fb2 = (const float*)d_in[12];
  float* ws  = (float*)d_ws;
  float* out = (float*)d_out;

  prep<<<72, 256, 0, stream>>>(w1, ow1, w2, ow2, ws);
  stage1<<<784, 256, 0, stream>>>(x, ob1, b1, ws, ws + WS_H1);
  stage2<<<NB, 256, 0, stream>>>(ws + WS_H1, ob2, b2, ws, ws + WS_H2);
  fc1<<<512, 256, 0, stream>>>(ws + WS_H2, fw1, ws + WS_PART);
  fcfinal<<<1024, 128, 0, stream>>>(ws + WS_PART, fb1, fw2, fb2, out);
}

// Round 4
// 383.250 us; speedup vs baseline: 1.6075x; 1.0064x over previous
//
#include <hip/hip_runtime.h>

// ---- sizes ----
// x: (1024,1,28,28); h1: (1024,32,14,14); h2: (1024,64,14,14)->12544; out: (1024,10)
#define NB 1024
#define TOTAL1 (NB*196)
#define SPS 200  // Sbuf pixel stride (196 real + 4 zero-pad; +8 guard at end)

// ws layout (float offsets)
#define WS_H1   0               // 1024*32*196      = 6422528
#define WS_H2   6422528         // 1024*12544      = 12845056
#define WS_PART 19267584        // 32*1024*128     = 4194304
#define WS_W1T  23461888        // 288
#define WS_OW1T 23462176        // 162
#define WS_W2T  23462338        // 18432  [k=ci*9+kk][co=64]
#define WS_OW2T 23480770        // 5184   [k=ci*9+j][c=18]

// ---------------- weight transpose prep ----------------
__global__ __launch_bounds__(256) void prep(const float* __restrict__ w1,
                                            const float* __restrict__ ow1,
                                            const float* __restrict__ w2,
                                            const float* __restrict__ ow2,
                                            float* __restrict__ ws) {
  int i = blockIdx.x * 256 + threadIdx.x;
  if (i < 288)   { int co = i / 9,  kk = i % 9;   ws[WS_W1T  + kk * 32 + co] = w1[i]; }
  if (i < 162)   { int c  = i / 9,  j  = i % 9;   ws[WS_OW1T + j  * 18 + c ] = ow1[i]; }
  if (i < 18432) { int co = i / 288, k = i % 288; ws[WS_W2T  + k  * 64 + co] = w2[i]; }
  if (i < 5184)  { int c  = i / 288, k = i % 288; ws[WS_OW2T + k  * 18 + c ] = ow2[i]; }
}

// ---------------- stage 1: offset conv + deform conv (1->32) + relu + pool 28->14 ----------------
__global__ __launch_bounds__(256, 2) void stage1(const float* __restrict__ x,
                                                 const float* __restrict__ ob1,
                                                 const float* __restrict__ b1,
                                                 const float* __restrict__ ws,
                                                 float* __restrict__ h1) {
  __shared__ float ximg[3 * 784];
  const float* __restrict__ w1t  = ws + WS_W1T;   // [kk][32]
  const float* __restrict__ ow1t = ws + WS_OW1T;  // [j][18]
  int tid = threadIdx.x;
  int g0 = blockIdx.x * 256;
  int bfirst = g0 / 196;
  for (int idx = tid; idx < 3 * 784; idx += 256) {
    int img = idx / 784;
    int b = bfirst + img;
    ximg[idx] = (b < NB) ? x[b * 784 + (idx - img * 784)] : 0.f;
  }
  __syncthreads();
  int g = g0 + tid;
  if (g >= TOTAL1) return;
  int b = g / 196, p = g - b * 196;
  const float* im = ximg + (b - bfirst) * 784;
  int oy = p / 14, ox = p - (p / 14) * 14;

  float pooled[32];
#pragma unroll
  for (int co = 0; co < 32; ++co) pooled[co] = 0.f;

  for (int sub = 0; sub < 4; ++sub) {
    int y  = 2 * oy + (sub >> 1);
    int ix = 2 * ox + (sub & 1);
    float patch[9];
#pragma unroll
    for (int j = 0; j < 9; ++j) {
      int yy = y + j / 3 - 1, xc = ix + j % 3 - 1;
      bool ok = (yy >= 0) & (yy < 28) & (xc >= 0) & (xc < 28);
      patch[j] = ok ? im[yy * 28 + xc] : 0.f;
    }
    float off[18];
#pragma unroll
    for (int c = 0; c < 18; ++c) off[c] = ob1[c];
#pragma unroll
    for (int j = 0; j < 9; ++j) {
      float v = patch[j];
#pragma unroll
      for (int c = 0; c < 18; ++c) off[c] = fmaf(v, ow1t[j * 18 + c], off[c]);
    }
    float a[32];
#pragma unroll
    for (int co = 0; co < 32; ++co) a[co] = b1[co];
#pragma unroll
    for (int kk = 0; kk < 9; ++kk) {
      float py = (float)(y - 1 + kk / 3) + off[2 * kk];
      float px = (float)(ix - 1 + kk % 3) + off[2 * kk + 1];
      float y0f = floorf(py), x0f = floorf(px);
      float wy1 = py - y0f, wx1 = px - x0f;
      float wy0 = 1.f - wy1, wx0 = 1.f - wx1;
      int y0 = (int)y0f, x0 = (int)x0f;
      int y1 = y0 + 1, x1 = x0 + 1;
      bool vy0 = (y0 >= 0) & (y0 < 28), vy1 = (y1 >= 0) & (y1 < 28);
      bool vx0 = (x0 >= 0) & (x0 < 28), vx1 = (x1 >= 0) & (x1 < 28);
      float W00 = (vy0 & vx0) ? wy0 * wx0 : 0.f;
      float W01 = (vy0 & vx1) ? wy0 * wx1 : 0.f;
      float W10 = (vy1 & vx0) ? wy1 * wx0 : 0.f;
      float W11 = (vy1 & vx1) ? wy1 * wx1 : 0.f;
      int yc0 = min(max(y0, 0), 27), yc1 = min(max(y1, 0), 27);
      int xc0 = min(max(x0, 0), 27), xc1 = min(max(x1, 0), 27);
      float s = im[yc0 * 28 + xc0] * W00 + im[yc0 * 28 + xc1] * W01 +
                im[yc1 * 28 + xc0] * W10 + im[yc1 * 28 + xc1] * W11;
#pragma unroll
      for (int co = 0; co < 32; ++co) a[co] = fmaf(s, w1t[kk * 32 + co], a[co]);
    }
#pragma unroll
    for (int co = 0; co < 32; ++co) pooled[co] += fmaxf(a[co], 0.f);
  }
#pragma unroll
  for (int co = 0; co < 32; ++co) h1[b * 6272 + co * 196 + p] = pooled[co] * 0.25f;
}

// ---------------- stage 2 v4: 3 blocks/CU via LDS diet; transient per-tap offsets ----------------
// LDS: imgT 25088B + Sbuf 25632B + offT 1664B = 52384B -> 3 blocks/CU (12 waves).
// Offset-GEMM accumulators stay in registers; tap kk's 2 channels published to offT
// by the threads owning oc=2kk/2kk+1 just before the tap consumes them.
__global__ __launch_bounds__(256, 3) void stage2(const float* __restrict__ h1,
                                                 const float* __restrict__ ob2,
                                                 const float* __restrict__ b2,
                                                 const float* __restrict__ ws,
                                                 float* __restrict__ h2) {
  __shared__ float imgT[196 * 32];       // imgT[p*32 + ((ci+4p)&31)] = img[ci][p]
  __shared__ float Sbuf[32 * SPS + 8];   // S[ci*SPS + p]; +8 guard for pg=12 over-reads
  __shared__ float offT[2 * 208];        // current tap's (dy,dx); 208-stride keeps spills in-row
  const float* __restrict__ w2t  = ws + WS_W2T;
  const float* __restrict__ ow2t = ws + WS_OW2T;
  int tid = threadIdx.x;
  int b = blockIdx.x;

  // ---- phase 1: load image, transposed + bank-rotated ----
  for (int e = tid; e < 6272; e += 256) {
    int ci = e / 196, p = e - ci * 196;
    imgT[p * 32 + ((ci + 4 * p) & 31)] = h1[b * 6272 + e];
  }

  // sampler identity
  int pp = tid;
  int spy = pp / 14, spx = pp - (pp / 14) * 14;

  // offset-GEMM identity: 18 channels x 13 pixel-groups of 16 = 234 threads
  int oc  = tid % 18;
  int opg = tid / 18;
  int op0 = opg * 16;
  bool oact = (tid < 234);
  float oacc[16];
#pragma unroll
  for (int i = 0; i < 16; ++i) oacc[i] = 0.f;

  // ---- phase 2: offset conv as 9 broadcast-GEMM taps (integer shifts) ----
  for (int j = 0; j < 9; ++j) {
    __syncthreads();
    if (pp < 196) {
      int yy = spy + j / 3 - 1, xx = spx + j % 3 - 1;
      bool ok = (yy >= 0) & (yy < 14) & (xx >= 0) & (xx < 14);
      int idx = ok ? (yy * 14 + xx) : 0;
      const float* src = imgT + idx * 32;
      int rot = (4 * idx) & 31;
#pragma unroll
      for (int cg = 0; cg < 8; ++cg) {
        float4 v;
        if (ok) v = *(const float4*)(src + ((cg * 4 + rot) & 31));
        else    v = make_float4(0.f, 0.f, 0.f, 0.f);
        Sbuf[(cg * 4 + 0) * SPS + pp] = v.x;
        Sbuf[(cg * 4 + 1) * SPS + pp] = v.y;
        Sbuf[(cg * 4 + 2) * SPS + pp] = v.z;
        Sbuf[(cg * 4 + 3) * SPS + pp] = v.w;
      }
    } else if (pp < SPS) {
#pragma unroll
      for (int ci2 = 0; ci2 < 32; ++ci2) Sbuf[ci2 * SPS + pp] = 0.f;
    }
    __syncthreads();
    if (oact) {
      float wv[32];
#pragma unroll
      for (int ci2 = 0; ci2 < 32; ++ci2) wv[ci2] = ow2t[(ci2 * 9 + j) * 18 + oc];
      for (int ci2 = 0; ci2 < 32; ++ci2) {
        const float* srow = Sbuf + ci2 * SPS + op0;
        float w = wv[ci2];
#pragma unroll
        for (int t = 0; t < 4; ++t) {
          float4 s = *(const float4*)(srow + 4 * t);
          oacc[4 * t + 0] = fmaf(w, s.x, oacc[4 * t + 0]);
          oacc[4 * t + 1] = fmaf(w, s.y, oacc[4 * t + 1]);
          oacc[4 * t + 2] = fmaf(w, s.z, oacc[4 * t + 2]);
          oacc[4 * t + 3] = fmaf(w, s.w, oacc[4 * t + 3]);
        }
      }
    }
  }

  // ---- phase 3: 9 taps of publish-offsets -> sample -> register-tiled broadcast GEMM ----
  int cog = tid & 15, pg = tid >> 4;
  int co0 = cog * 4;
  int p0 = pg * 16;
  bool gact = (pg < 13);
  float acc[4][16];
  {
    float4 bb = *(const float4*)(b2 + co0);
    float bj[4] = {bb.x, bb.y, bb.z, bb.w};
#pragma unroll
    for (int jj = 0; jj < 4; ++jj)
#pragma unroll
      for (int i = 0; i < 16; ++i) acc[jj][i] = bj[jj];
  }
  float myob = oact ? ob2[oc] : 0.f;

  for (int kk = 0; kk < 9; ++kk) {
    __syncthreads();  // prev GEMM done with Sbuf; prev sampler done with offT
    if (oact && (oc >> 1) == kk) {
      float* dst = offT + (oc & 1) * 208 + op0;
#pragma unroll
      for (int i = 0; i < 16; ++i) dst[i] = oacc[i] + myob;
    }
    __syncthreads();  // offT ready
    if (pp < 196) {
      float dyv = offT[pp];
      float dxv = offT[208 + pp];
      float pyv = (float)(spy - 1 + kk / 3) + dyv;
      float pxv = (float)(spx - 1 + kk % 3) + dxv;
      float y0f = floorf(pyv), x0f = floorf(pxv);
      float wy1 = pyv - y0f, wx1 = pxv - x0f;
      float wy0 = 1.f - wy1, wx0 = 1.f - wx1;
      int y0 = (int)y0f, x0 = (int)x0f;
      int y1 = y0 + 1, x1 = x0 + 1;
      bool vy0 = (y0 >= 0) & (y0 < 14), vy1 = (y1 >= 0) & (y1 < 14);
      bool vx0 = (x0 >= 0) & (x0 < 14), vx1 = (x1 >= 0) & (x1 < 14);
      float W00 = (vy0 & vx0) ? wy0 * wx0 : 0.f;
      float W01 = (vy0 & vx1) ? wy0 * wx1 : 0.f;
      float W10 = (vy1 & vx0) ? wy1 * wx0 : 0.f;
      float W11 = (vy1 & vx1) ? wy1 * wx1 : 0.f;
      int yc0 = min(max(y0, 0), 13), yc1 = min(max(y1, 0), 13);
      int xc0 = min(max(x0, 0), 13), xc1 = min(max(x1, 0), 13);
      int i00 = yc0 * 14 + xc0, i01 = yc0 * 14 + xc1;
      int i10 = yc1 * 14 + xc0, i11 = yc1 * 14 + xc1;
      const float* s00 = imgT + i00 * 32; int r00 = (4 * i00) & 31;
      const float* s01 = imgT + i01 * 32; int r01 = (4 * i01) & 31;
      const float* s10 = imgT + i10 * 32; int r10 = (4 * i10) & 31;
      const float* s11 = imgT + i11 * 32; int r11 = (4 * i11) & 31;
#pragma unroll
      for (int cg = 0; cg < 8; ++cg) {
        float4 a0 = *(const float4*)(s00 + ((cg * 4 + r00) & 31));
        float4 a1 = *(const float4*)(s01 + ((cg * 4 + r01) & 31));
        float4 a2 = *(const float4*)(s10 + ((cg * 4 + r10) & 31));
        float4 a3 = *(const float4*)(s11 + ((cg * 4 + r11) & 31));
        Sbuf[(cg * 4 + 0) * SPS + pp] = fmaf(W00, a0.x, fmaf(W01, a1.x, fmaf(W10, a2.x, W11 * a3.x)));
        Sbuf[(cg * 4 + 1) * SPS + pp] = fmaf(W00, a0.y, fmaf(W01, a1.y, fmaf(W10, a2.y, W11 * a3.y)));
        Sbuf[(cg * 4 + 2) * SPS + pp] = fmaf(W00, a0.z, fmaf(W01, a1.z, fmaf(W10, a2.z, W11 * a3.z)));
        Sbuf[(cg * 4 + 3) * SPS + pp] = fmaf(W00, a0.w, fmaf(W01, a1.w, fmaf(W10, a2.w, W11 * a3.w)));
      }
    } else if (pp < SPS) {
#pragma unroll
      for (int ci2 = 0; ci2 < 32; ++ci2) Sbuf[ci2 * SPS + pp] = 0.f;
    }
    __syncthreads();
    if (gact) {
      // 32 ci in chunks of 4: preload 4 weight quads (VMEM, L2-hit), then FMA
      for (int cb = 0; cb < 32; cb += 4) {
        float4 w[4];
#pragma unroll
        for (int u = 0; u < 4; ++u)
          w[u] = *(const float4*)(w2t + ((cb + u) * 9 + kk) * 64 + co0);
#pragma unroll
        for (int u = 0; u < 4; ++u) {
          const float* srow = Sbuf + (cb + u) * SPS + p0;
          float4 s0 = *(const float4*)(srow);
          float4 s1 = *(const float4*)(srow + 4);
          float4 s2 = *(const float4*)(srow + 8);
          float4 s3 = *(const float4*)(srow + 12);
          float sv[16] = {s0.x, s0.y, s0.z, s0.w, s1.x, s1.y, s1.z, s1.w,
                          s2.x, s2.y, s2.z, s2.w, s3.x, s3.y, s3.z, s3.w};
          float wj[4] = {w[u].x, w[u].y, w[u].z, w[u].w};
#pragma unroll
          for (int jj = 0; jj < 4; ++jj)
#pragma unroll
            for (int i = 0; i < 16; ++i)
              acc[jj][i] = fmaf(wj[jj], sv[i], acc[jj][i]);
        }
      }
    }
  }

  // ---- phase 4: ReLU + direct float4 global stores ----
  if (gact) {
    float* __restrict__ orow = h2 + b * 12544 + co0 * 196 + p0;
#pragma unroll
    for (int jj = 0; jj < 4; ++jj) {
#pragma unroll
      for (int t = 0; t < 4; ++t) {
        if (p0 + 4 * t < 196) {
          float4 v;
          v.x = fmaxf(acc[jj][4 * t + 0], 0.f);
          v.y = fmaxf(acc[jj][4 * t + 1], 0.f);
          v.z = fmaxf(acc[jj][4 * t + 2], 0.f);
          v.w = fmaxf(acc[jj][4 * t + 3], 0.f);
          *(float4*)(orow + jj * 196 + 4 * t) = v;
        }
      }
    }
  }
}

// ---------------- fc1: K-split GEMM 1024x128, K=12544 -> partials[32][1024][128] ----------------
__global__ __launch_bounds__(256, 2) void fc1(const float* __restrict__ h2,
                                              const float* __restrict__ fw1,
                                              float* __restrict__ part) {
  __shared__ float a_s[56 * 72];   // [k][r]
  __shared__ float b_s[56 * 132];  // [k][c]
  int tid = threadIdx.x;
  int rb = (blockIdx.x & 15) * 64;
  int ks = blockIdx.x >> 4;
  int kbase = ks * 392;
  int c0 = (tid & 31) * 4;
  int r0 = (tid >> 5) * 8;

  float acc[8][4];
#pragma unroll
  for (int i = 0; i < 8; ++i)
#pragma unroll
    for (int j = 0; j < 4; ++j) acc[i][j] = 0.f;

  for (int ch = 0; ch < 7; ++ch) {
    int kb = kbase + ch * 56;
    __syncthreads();
#pragma unroll
    for (int t = 0; t < 14; ++t) {
      int idx = t * 256 + tid;
      int r = idx / 56, k = idx - r * 56;
      a_s[k * 72 + r] = h2[(rb + r) * 12544 + kb + k];
    }
#pragma unroll
    for (int t = 0; t < 28; ++t) {
      int idx = t * 256 + tid;
      int c = idx / 56, k = idx - c * 56;
      b_s[k * 132 + c] = fw1[c * 12544 + kb + k];
    }
    __syncthreads();
    for (int k = 0; k < 56; ++k) {
      float4 bv = *(const float4*)&b_s[k * 132 + c0];
      float4 av0 = *(const float4*)&a_s[k * 72 + r0];
      float4 av1 = *(const float4*)&a_s[k * 72 + r0 + 4];
      float av[8] = {av0.x, av0.y, av0.z, av0.w, av1.x, av1.y, av1.z, av1.w};
      float bj[4] = {bv.x, bv.y, bv.z, bv.w};
#pragma unroll
      for (int i = 0; i < 8; ++i)
#pragma unroll
        for (int j = 0; j < 4; ++j) acc[i][j] = fmaf(av[i], bj[j], acc[i][j]);
    }
  }
#pragma unroll
  for (int i = 0; i < 8; ++i) {
    int r = rb + r0 + i;
#pragma unroll
    for (int j = 0; j < 4; ++j)
      part[(ks * 1024 + r) * 128 + c0 + j] = acc[i][j];
  }
}

// ---------------- reduce partials + bias + relu + fc2 ----------------
__global__ __launch_bounds__(128) void fcfinal(const float* __restrict__ part,
                                               const float* __restrict__ fb1,
                                               const float* __restrict__ fw2,
                                               const float* __restrict__ fb2,
                                               float* __restrict__ out) {
  __shared__ float tbuf[128];
  int b = blockIdx.x, c = threadIdx.x;
  float s = fb1[c];
  for (int ks = 0; ks < 32; ++ks) s += part[(ks * 1024 + b) * 128 + c];
  tbuf[c] = fmaxf(s, 0.f);
  __syncthreads();
  if (c < 10) {
    float v = fb2[c];
#pragma unroll
    for (int k = 0; k < 128; ++k) v = fmaf(tbuf[k], fw2[c * 128 + k], v);
    out[b * 10 + c] = v;
  }
}

extern "C" void kernel_launch(void* const* d_in, const int* in_sizes, int n_in,
                              void* d_out, int out_size, void* d_ws, size_t ws_size,
                              hipStream_t stream) {
  const float* x   = (const float*)d_in[0];
  const float* ow1 = (const float*)d_in[1];
  const float* ob1 = (const float*)d_in[2];
  const float* w1  = (const float*)d_in[3];
  const float* b1  = (const float*)d_in[4];
  const float* ow2 = (const float*)d_in[5];
  const float* ob2 = (const float*)d_in[6];
  const float* w2  = (const float*)d_in[7];
  const float* b2  = (const float*)d_in[8];
  const float* fw1 = (const float*)d_in[9];
  const float* fb1 = (const float*)d_in[10];
  const float* fw2 = (const float*)d_in[11];
  const float* fb2 = (const float*)d_in[12];
  float* ws  = (float*)d_ws;
  float* out = (float*)d_out;

  prep<<<72, 256, 0, stream>>>(w1, ow1, w2, ow2, ws);
  stage1<<<784, 256, 0, stream>>>(x, ob1, b1, ws, ws + WS_H1);
  stage2<<<NB, 256, 0, stream>>>(ws + WS_H1, ob2, b2, ws, ws + WS_H2);
  fc1<<<512, 256, 0, stream>>>(ws + WS_H2, fw1, ws + WS_PART);
  fcfinal<<<1024, 128, 0, stream>>>(ws + WS_PART, fb1, fw2, fb2, out);
}